// Round 2
// baseline (361.309 us; speedup 1.0000x reference)
//
#include <hip/hip_runtime.h>
#include <hip/hip_bf16.h>

#define LOG2E 1.4426950408889634f
#define LN2   0.6931471805599453f
#define BIGP  (1.0e10f * LOG2E)   // BIG scaled into log2-domain

// Problem constants
#define BATCH 32
#define SEQ   512
#define DIM   128
#define NMAT  128                  // 4 pairs * 32 batches
#define MAT_ELEMS (SEQ * SEQ)      // 262144 floats per matrix

// hw exp2 / log2 (v_exp_f32 / v_log_f32)
#define EXP2F(x) __builtin_amdgcn_exp2f(x)
#define LOG2F(x) __builtin_amdgcn_logf(x)

// ---------------------------------------------------------------------------
// Kernel 1: per-row inverse norms:  invn[set][b][t] = 1/(||v||+1e-8)
// sets: 0=TGT, 1=OTH, 2=X. One wave per row.
// ---------------------------------------------------------------------------
__global__ __launch_bounds__(256) void norm_kernel(
    const float* __restrict__ tgt, const float* __restrict__ oth,
    const float* __restrict__ x, float* __restrict__ invn) {
  int gid  = blockIdx.x * blockDim.x + threadIdx.x;
  int wave = gid >> 6;
  int lane = threadIdx.x & 63;
  if (wave >= 3 * BATCH * SEQ) return;
  int set = wave / (BATCH * SEQ);
  int row = wave % (BATCH * SEQ);
  const float* src = (set == 0) ? tgt : ((set == 1) ? oth : x);
  const float2* p = (const float2*)(src + (size_t)row * DIM);
  float2 v = p[lane];                       // 64 lanes * 2 = 128 elems
  float s = v.x * v.x + v.y * v.y;
#pragma unroll
  for (int off = 32; off; off >>= 1) s += __shfl_xor(s, off);
  if (lane == 0) invn[wave] = 1.0f / (sqrtf(s) + 1e-8f);
}

// ---------------------------------------------------------------------------
// Kernel 2: cost matrices in skewed layout, premultiplied by log2(e).
//   Dsk[m][(i+j+2)&511][i]  (i,j 0-based seq indices)
// pairs: p0 = OTH x X, p1 = TGT x X, p2 = OTH x OTH, p3 = TGT x TGT
// 64x64 tile per 256-thread block, K=128 fully staged in LDS (K-major).
// ---------------------------------------------------------------------------
__global__ __launch_bounds__(256) void cost_kernel(
    const float* __restrict__ tgt, const float* __restrict__ oth,
    const float* __restrict__ x, const float* __restrict__ invn,
    float* __restrict__ Dsk) {
  __shared__ float As[DIM][64];
  __shared__ float Bs[DIM][64];

  int m = blockIdx.z;
  int p = m >> 5, b = m & 31;
  int setA = (p == 1 || p == 3) ? 0 : 1;               // TGT for p1,p3 else OTH
  int setB = (p <= 1) ? 2 : setA;                      // X for cross pairs, self otherwise
  const float* baseA = ((setA == 0) ? tgt : oth) + (size_t)b * SEQ * DIM;
  const float* baseB = ((setB == 0) ? tgt : (setB == 1) ? oth : x) + (size_t)b * SEQ * DIM;
  const float* invA = invn + (size_t)setA * (BATCH * SEQ) + b * SEQ;
  const float* invB = invn + (size_t)setB * (BATCH * SEQ) + b * SEQ;

  int i0 = blockIdx.x * 64, j0 = blockIdx.y * 64;
  int t = threadIdx.x;

  // stage: thread t handles row r=t>>2, k-quarter kq=t&3 ; 8 iterations
  int r = t >> 2, kq = t & 3;
#pragma unroll
  for (int kb = 0; kb < 8; ++kb) {
    int k4 = kb * 16 + kq * 4;
    float4 ga = *(const float4*)(baseA + (size_t)(i0 + r) * DIM + k4);
    float4 gb = *(const float4*)(baseB + (size_t)(j0 + r) * DIM + k4);
    As[k4 + 0][r] = ga.x; As[k4 + 1][r] = ga.y; As[k4 + 2][r] = ga.z; As[k4 + 3][r] = ga.w;
    Bs[k4 + 0][r] = gb.x; Bs[k4 + 1][r] = gb.y; Bs[k4 + 2][r] = gb.z; Bs[k4 + 3][r] = gb.w;
  }
  __syncthreads();

  int tr = t >> 4, tc = t & 15;                        // 4x4 micro-tile
  float acc[4][4] = {};
#pragma unroll 4
  for (int kk = 0; kk < DIM; ++kk) {
    float4 a4 = *(const float4*)(&As[kk][tr << 2]);
    float4 b4 = *(const float4*)(&Bs[kk][tc << 2]);
    float av[4] = {a4.x, a4.y, a4.z, a4.w};
    float bv[4] = {b4.x, b4.y, b4.z, b4.w};
#pragma unroll
    for (int rr = 0; rr < 4; ++rr)
#pragma unroll
      for (int cc = 0; cc < 4; ++cc)
        acc[rr][cc] = fmaf(av[rr], bv[cc], acc[rr][cc]);
  }

  float* Dm = Dsk + (size_t)m * MAT_ELEMS;
#pragma unroll
  for (int rr = 0; rr < 4; ++rr) {
    int ia = i0 + (tr << 2) + rr;
    float iA = invA[ia];
#pragma unroll
    for (int cc = 0; cc < 4; ++cc) {
      int ja = j0 + (tc << 2) + cc;
      float dp = (1.0f - acc[rr][cc] * iA * invB[ja]) * LOG2E;
      Dm[(((ia + ja + 2) & 511) << 9) + ia] = dp;
    }
  }
}

// ---------------------------------------------------------------------------
// Kernel 3: wavefront soft-DTW in log2 domain. One 512-thread WG per matrix.
// buf[x][i] holds R'[i][k-i] for rotating diagonals. 1024 diagonal steps.
// ---------------------------------------------------------------------------
__device__ __forceinline__ void wg_barrier() {
  // LDS-visibility barrier that does NOT drain vmcnt (keeps D-prefetch in flight)
  asm volatile("s_waitcnt lgkmcnt(0)" ::: "memory");
  __builtin_amdgcn_s_barrier();
  asm volatile("" ::: "memory");
}

__global__ __launch_bounds__(512) void dtw_kernel(
    const float* __restrict__ Dsk, float* __restrict__ raw) {
  __shared__ float buf0[513], buf1[513], buf2[513];
  int m = blockIdx.x;
  const float* Dm = Dsk + (size_t)m * MAT_ELEMS;
  int tid = threadIdx.x;                     // handles DTW row i = tid+1

  buf0[tid] = BIGP;
  buf1[tid] = (tid == 0) ? 0.0f : BIGP;      // diagonal k=0: R[0][0]=0
  buf2[tid] = BIGP;
  if (tid == 0) { buf0[512] = BIGP; buf1[512] = BIGP; buf2[512] = BIGP; }
  wg_barrier();

  float* p2 = buf0; float* p1 = buf1; float* nw = buf2;
  float dnext = Dm[((1 & 511) << 9) + tid];  // prefetch diagonal k=1
  float result = 0.0f;

  for (int k = 1; k <= 1024; ++k) {
    float dcur = dnext;
    if (k < 1024) dnext = Dm[(((k + 1) & 511) << 9) + tid];  // prefetch next diag
    float a  = p1[tid];       // R'[i-1][j]
    float bb = p1[tid + 1];   // R'[i][j-1]
    float c  = p2[tid];       // R'[i-1][j-1]
    float mn = fminf(fminf(a, bb), c);
    float s  = EXP2F(mn - a) + EXP2F(mn - bb) + EXP2F(mn - c);
    float v  = dcur + (mn - LOG2F(s));
    int j = k - (tid + 1);
    v = (j >= 1 && j <= SEQ) ? v : BIGP;
    nw[tid + 1] = v;
    if (tid == 0) nw[0] = BIGP;
    wg_barrier();
    if (k == 1024) result = v;               // tid 511: R'[512][512]
    float* tmp = p2; p2 = p1; p1 = nw; nw = tmp;
  }
  if (tid == 511) raw[m] = result * LN2;
}

// ---------------------------------------------------------------------------
// Kernel 4: diff[b] = raw0 - raw1 - 0.5*raw2 + 0.5*raw3 ; out = mean((diff-l)^2)
// ---------------------------------------------------------------------------
__global__ __launch_bounds__(64) void combine_kernel(
    const float* __restrict__ raw, const float* __restrict__ labels,
    float* __restrict__ out) {
  int lane = threadIdx.x;
  float val = 0.0f;
  if (lane < BATCH) {
    float r0 = raw[0 * BATCH + lane];
    float r1 = raw[1 * BATCH + lane];
    float r2 = raw[2 * BATCH + lane];
    float r3 = raw[3 * BATCH + lane];
    float diff = r0 - r1 - 0.5f * r2 + 0.5f * r3;
    float e = diff - labels[lane];
    val = e * e;
  }
#pragma unroll
  for (int off = 32; off; off >>= 1) val += __shfl_xor(val, off);
  if (lane == 0) out[0] = val * (1.0f / BATCH);
}

// ---------------------------------------------------------------------------
extern "C" void kernel_launch(void* const* d_in, const int* in_sizes, int n_in,
                              void* d_out, int out_size, void* d_ws, size_t ws_size,
                              hipStream_t stream) {
  const float* TGT = (const float*)d_in[0];
  const float* OTH = (const float*)d_in[1];
  const float* X   = (const float*)d_in[2];
  const float* labels = (const float*)d_in[3];
  float* out = (float*)d_out;

  char* ws = (char*)d_ws;
  float* Dsk  = (float*)ws;                                  // 128 MB
  float* invn = (float*)(ws + (size_t)NMAT * MAT_ELEMS * 4); // 192 KB
  float* raw  = (float*)(ws + (size_t)NMAT * MAT_ELEMS * 4 + 3 * BATCH * SEQ * 4);

  hipLaunchKernelGGL(norm_kernel, dim3((3 * BATCH * SEQ) / 4), dim3(256), 0, stream,
                     TGT, OTH, X, invn);
  hipLaunchKernelGGL(cost_kernel, dim3(8, 8, NMAT), dim3(256), 0, stream,
                     TGT, OTH, X, invn, Dsk);
  hipLaunchKernelGGL(dtw_kernel, dim3(NMAT), dim3(512), 0, stream, Dsk, raw);
  hipLaunchKernelGGL(combine_kernel, dim3(1), dim3(64), 0, stream, raw, labels, out);
}

// Round 3
// 341.274 us; speedup vs baseline: 1.0587x; 1.0587x over previous
//
#include <hip/hip_runtime.h>
#include <hip/hip_bf16.h>

#define LOG2E 1.4426950408889634f
#define LN2   0.6931471805599453f
#define BIGP  (1.0e10f * LOG2E)   // BIG scaled into log2-domain

// Problem constants
#define BATCH 32
#define SEQ   512
#define DIM   128
#define NMAT  128                  // 4 pairs * 32 batches
#define MAT_ELEMS (SEQ * SEQ)      // 262144 floats per matrix

// hw exp2 / log2 (v_exp_f32 / v_log_f32)
#define EXP2F(x) __builtin_amdgcn_exp2f(x)
#define LOG2F(x) __builtin_amdgcn_logf(x)

// ---------------------------------------------------------------------------
// Kernel 1: per-row inverse norms:  invn[set][b][t] = 1/(||v||+1e-8)
// ---------------------------------------------------------------------------
__global__ __launch_bounds__(256) void norm_kernel(
    const float* __restrict__ tgt, const float* __restrict__ oth,
    const float* __restrict__ x, float* __restrict__ invn) {
  int gid  = blockIdx.x * blockDim.x + threadIdx.x;
  int wave = gid >> 6;
  int lane = threadIdx.x & 63;
  if (wave >= 3 * BATCH * SEQ) return;
  int set = wave / (BATCH * SEQ);
  int row = wave % (BATCH * SEQ);
  const float* src = (set == 0) ? tgt : ((set == 1) ? oth : x);
  const float2* p = (const float2*)(src + (size_t)row * DIM);
  float2 v = p[lane];
  float s = v.x * v.x + v.y * v.y;
#pragma unroll
  for (int off = 32; off; off >>= 1) s += __shfl_xor(s, off);
  if (lane == 0) invn[wave] = 1.0f / (sqrtf(s) + 1e-8f);
}

// ---------------------------------------------------------------------------
// Kernel 2: cost matrices in skewed layout, premultiplied by log2(e).
//   Dsk[m][(i+j)&511][i]  for 1-based DTW cell (i,j) -> stored at row (i+j)&511, col i-1
// ---------------------------------------------------------------------------
__global__ __launch_bounds__(256) void cost_kernel(
    const float* __restrict__ tgt, const float* __restrict__ oth,
    const float* __restrict__ x, const float* __restrict__ invn,
    float* __restrict__ Dsk) {
  __shared__ float As[DIM][64];
  __shared__ float Bs[DIM][64];

  int m = blockIdx.z;
  int p = m >> 5, b = m & 31;
  int setA = (p == 1 || p == 3) ? 0 : 1;
  int setB = (p <= 1) ? 2 : setA;
  const float* baseA = ((setA == 0) ? tgt : oth) + (size_t)b * SEQ * DIM;
  const float* baseB = ((setB == 0) ? tgt : (setB == 1) ? oth : x) + (size_t)b * SEQ * DIM;
  const float* invA = invn + (size_t)setA * (BATCH * SEQ) + b * SEQ;
  const float* invB = invn + (size_t)setB * (BATCH * SEQ) + b * SEQ;

  int i0 = blockIdx.x * 64, j0 = blockIdx.y * 64;
  int t = threadIdx.x;

  int r = t >> 2, kq = t & 3;
#pragma unroll
  for (int kb = 0; kb < 8; ++kb) {
    int k4 = kb * 16 + kq * 4;
    float4 ga = *(const float4*)(baseA + (size_t)(i0 + r) * DIM + k4);
    float4 gb = *(const float4*)(baseB + (size_t)(j0 + r) * DIM + k4);
    As[k4 + 0][r] = ga.x; As[k4 + 1][r] = ga.y; As[k4 + 2][r] = ga.z; As[k4 + 3][r] = ga.w;
    Bs[k4 + 0][r] = gb.x; Bs[k4 + 1][r] = gb.y; Bs[k4 + 2][r] = gb.z; Bs[k4 + 3][r] = gb.w;
  }
  __syncthreads();

  int tr = t >> 4, tc = t & 15;
  float acc[4][4] = {};
#pragma unroll 4
  for (int kk = 0; kk < DIM; ++kk) {
    float4 a4 = *(const float4*)(&As[kk][tr << 2]);
    float4 b4 = *(const float4*)(&Bs[kk][tc << 2]);
    float av[4] = {a4.x, a4.y, a4.z, a4.w};
    float bv[4] = {b4.x, b4.y, b4.z, b4.w};
#pragma unroll
    for (int rr = 0; rr < 4; ++rr)
#pragma unroll
      for (int cc = 0; cc < 4; ++cc)
        acc[rr][cc] = fmaf(av[rr], bv[cc], acc[rr][cc]);
  }

  float* Dm = Dsk + (size_t)m * MAT_ELEMS;
#pragma unroll
  for (int rr = 0; rr < 4; ++rr) {
    int ia = i0 + (tr << 2) + rr;
    float iA = invA[ia];
#pragma unroll
    for (int cc = 0; cc < 4; ++cc) {
      int ja = j0 + (tc << 2) + cc;
      float dp = (1.0f - acc[rr][cc] * iA * invB[ja]) * LOG2E;
      Dm[(((ia + ja + 2) & 511) << 9) + ia] = dp;
    }
  }
}

// ---------------------------------------------------------------------------
// Kernel 3: staggered-wave soft-DTW. 8 waves/block, wave w lags w*J steps.
// Intra-wave communication via shfl_up; wave boundary via LDS ring.
// Thread tid owns DTW row i=tid+1. Cell (i,j) computed at step L=i+j.
//   a = R[i-1][j]   = lane-1's v at L-1  (shfl from previous step)
//   b = R[i][j-1]   = own v at L-1
//   c = R[i-1][j-1] = lane-1's v at L-2  (previous shfl result)
// Lane 0 gets a,c from the boundary stream b_w(s) = v of row 64w at step s,
// delivered via LDS ring (written by wave w-1's lane 63) + v_readlane.
// ---------------------------------------------------------------------------
#define JP 32          // steps per phase
#define NPH 40         // phases (wave 7 hits L=1024 at phase 38)

__device__ __forceinline__ void wg_barrier() {
  asm volatile("s_waitcnt lgkmcnt(0)" ::: "memory");
  __builtin_amdgcn_s_barrier();
  asm volatile("" ::: "memory");
}

__global__ __launch_bounds__(512) void dtw_kernel(
    const float* __restrict__ Dsk, float* __restrict__ raw) {
  __shared__ float ring[8][128];       // boundary stream ring, slot = s & 127
  const int tid  = threadIdx.x;
  const int w    = tid >> 6;
  const int lane = tid & 63;
  const int m    = blockIdx.x;
  const float* Dm = Dsk + (size_t)m * MAT_ELEMS;

  ((float*)ring)[tid]       = BIGP;
  ((float*)ring)[tid + 512] = BIGP;
  __syncthreads();

  const int i = tid + 1;               // my DTW row (1..512)
  const bool is0  = (lane == 0);
  const bool is63 = (lane == 63);
  const int  jj   = (lane <= JP) ? lane : JP;   // boundary-read lane clamp

  float v = BIGP, shp = BIGP, shp2 = BIGP;     // own prev, lane-1 prev, lane-1 prev2
  float res = 0.0f;

  float dA[JP], dB[JP];
  {
    int base0 = (0 - w) * JP;
#pragma unroll
    for (int l = 0; l < JP; ++l) {
      int L = base0 + 1 + l;
      dA[l] = Dm[((L & 511) << 9) + tid];
    }
  }

#define PHASE(P_, DC_, DN_)                                                   \
  {                                                                           \
    const int base = ((P_) - w) * JP;                                         \
    float bvec;                                                               \
    if (w == 0) {                                                             \
      int s = base - 1 + jj;                                                  \
      bvec = (s == 0) ? 0.0f : BIGP;                                          \
    } else {                                                                  \
      bvec = ring[w - 1][(base - 1 + jj) & 127];                              \
    }                                                                         \
    _Pragma("unroll")                                                         \
    for (int l = 0; l < JP; ++l) {      /* prefetch next phase's D */         \
      int L = base + JP + 1 + l;                                              \
      DN_[l] = Dm[((L & 511) << 9) + tid];                                    \
    }                                                                         \
    _Pragma("unroll")                                                         \
    for (int l = 1; l <= JP; ++l) {                                           \
      float s_a = __int_as_float(                                             \
          __builtin_amdgcn_readlane(__float_as_int(bvec), l));                \
      float s_c = __int_as_float(                                             \
          __builtin_amdgcn_readlane(__float_as_int(bvec), l - 1));            \
      float a = is0 ? s_a : shp;                                              \
      float c = is0 ? s_c : shp2;                                             \
      float b = v;                                                            \
      float mn = fminf(fminf(a, b), c);                                       \
      float sum = EXP2F(mn - a) + EXP2F(mn - b) + EXP2F(mn - c);              \
      float nv = DC_[l - 1] + (mn - LOG2F(sum));                              \
      int L = base + l;                                                       \
      unsigned ju = (unsigned)(L - i - 1);  /* valid iff j-1 in [0,511] */    \
      nv = (ju < 512u) ? nv : BIGP;                                           \
      if (L == 1024 && tid == 511) res = nv;                                  \
      if (is63) ring[w][L & 127] = nv;                                        \
      shp2 = shp;                                                             \
      shp = __shfl_up(nv, 1);                                                 \
      v = nv;                                                                 \
    }                                                                         \
    wg_barrier();                                                             \
  }

  for (int p = 0; p < NPH; p += 2) {
    PHASE(p, dA, dB)
    PHASE(p + 1, dB, dA)
  }
#undef PHASE

  if (tid == 511) raw[m] = res * LN2;
}

// ---------------------------------------------------------------------------
// Kernel 4: diff[b] = raw0 - raw1 - 0.5*raw2 + 0.5*raw3 ; out = mean((diff-l)^2)
// ---------------------------------------------------------------------------
__global__ __launch_bounds__(64) void combine_kernel(
    const float* __restrict__ raw, const float* __restrict__ labels,
    float* __restrict__ out) {
  int lane = threadIdx.x;
  float val = 0.0f;
  if (lane < BATCH) {
    float r0 = raw[0 * BATCH + lane];
    float r1 = raw[1 * BATCH + lane];
    float r2 = raw[2 * BATCH + lane];
    float r3 = raw[3 * BATCH + lane];
    float diff = r0 - r1 - 0.5f * r2 + 0.5f * r3;
    float e = diff - labels[lane];
    val = e * e;
  }
#pragma unroll
  for (int off = 32; off; off >>= 1) val += __shfl_xor(val, off);
  if (lane == 0) out[0] = val * (1.0f / BATCH);
}

// ---------------------------------------------------------------------------
extern "C" void kernel_launch(void* const* d_in, const int* in_sizes, int n_in,
                              void* d_out, int out_size, void* d_ws, size_t ws_size,
                              hipStream_t stream) {
  const float* TGT = (const float*)d_in[0];
  const float* OTH = (const float*)d_in[1];
  const float* X   = (const float*)d_in[2];
  const float* labels = (const float*)d_in[3];
  float* out = (float*)d_out;

  char* ws = (char*)d_ws;
  float* Dsk  = (float*)ws;                                  // 128 MB
  float* invn = (float*)(ws + (size_t)NMAT * MAT_ELEMS * 4); // 192 KB
  float* raw  = (float*)(ws + (size_t)NMAT * MAT_ELEMS * 4 + 3 * BATCH * SEQ * 4);

  hipLaunchKernelGGL(norm_kernel, dim3((3 * BATCH * SEQ) / 4), dim3(256), 0, stream,
                     TGT, OTH, X, invn);
  hipLaunchKernelGGL(cost_kernel, dim3(8, 8, NMAT), dim3(256), 0, stream,
                     TGT, OTH, X, invn, Dsk);
  hipLaunchKernelGGL(dtw_kernel, dim3(NMAT), dim3(512), 0, stream, Dsk, raw);
  hipLaunchKernelGGL(combine_kernel, dim3(1), dim3(64), 0, stream, raw, labels, out);
}

// Round 4
// 247.886 us; speedup vs baseline: 1.4576x; 1.3767x over previous
//
#include <hip/hip_runtime.h>
#include <hip/hip_bf16.h>

#define LOG2E 1.4426950408889634f
#define LN2   0.6931471805599453f
#define BIGP  (1.0e10f * LOG2E)   // BIG scaled into log2-domain

#define BATCH 32
#define SEQ   512
#define DIM   128
#define NMAT  128                  // 4 pairs * 32 batches
#define MAT_ELEMS (SEQ * SEQ)

#define EXP2F(x) __builtin_amdgcn_exp2f(x)
#define LOG2F(x) __builtin_amdgcn_logf(x)

typedef short bf16x8 __attribute__((ext_vector_type(8)));
typedef float f32x4 __attribute__((ext_vector_type(4)));
typedef __attribute__((address_space(1))) const void gas_void;
typedef __attribute__((address_space(3))) void las_void;

// ---------------------------------------------------------------------------
// Kernel 1 (prep): normalize rows, split to bf16 hi/lo, interleave:
//   Y[row][2k] = hi_k, Y[row][2k+1] = lo_k   (K'=256 bf16 per row)
// One wave per row; 3 sets concatenated [set][b][t].
// ---------------------------------------------------------------------------
__device__ __forceinline__ unsigned short f2bf_rn(float f) {
  unsigned u = __float_as_uint(f);
  u = (u + 0x7FFF + ((u >> 16) & 1)) >> 16;
  return (unsigned short)u;
}
__device__ __forceinline__ float bf2f(unsigned short h) {
  return __uint_as_float(((unsigned)h) << 16);
}

__global__ __launch_bounds__(256) void prep_kernel(
    const float* __restrict__ tgt, const float* __restrict__ oth,
    const float* __restrict__ x, unsigned short* __restrict__ Y) {
  int gid  = blockIdx.x * blockDim.x + threadIdx.x;
  int wave = gid >> 6;
  int lane = threadIdx.x & 63;
  int set = wave / (BATCH * SEQ);
  int row = wave % (BATCH * SEQ);
  const float* src = (set == 0) ? tgt : ((set == 1) ? oth : x);
  const float2* p = (const float2*)(src + (size_t)row * DIM);
  float2 v = p[lane];
  float s = v.x * v.x + v.y * v.y;
#pragma unroll
  for (int off = 32; off; off >>= 1) s += __shfl_xor(s, off);
  float inv = 1.0f / (sqrtf(s) + 1e-8f);
  float y0 = v.x * inv, y1 = v.y * inv;
  unsigned short h0 = f2bf_rn(y0);
  unsigned short l0 = f2bf_rn(y0 - bf2f(h0));
  unsigned short h1 = f2bf_rn(y1);
  unsigned short l1 = f2bf_rn(y1 - bf2f(h1));
  ushort4 st = {h0, l0, h1, l1};
  ((ushort4*)(Y + (size_t)wave * 256))[lane] = st;
}

// ---------------------------------------------------------------------------
// Kernel 2 (costmm): bf16 MFMA GEMM, K'=256 (hi/lo interleaved), 128x128 tile,
// 4 waves (2x2 of 64x64). LDS slab = 128 rows x 64 bf16, XOR-swizzled via
// pre-swizzled global source (linear LDS dest for global_load_lds).
// Epilogue: cost=(1-dot)*LOG2E scattered into skewed layout
//   Dm[((ia+ja+2)&511)<<9 | ia]  (L2 absorbs the scatter).
// ---------------------------------------------------------------------------
__global__ __launch_bounds__(256) void costmm_kernel(
    const unsigned short* __restrict__ Y, float* __restrict__ Dsk) {
  __shared__ unsigned short As[128 * 64];
  __shared__ unsigned short Bs[128 * 64];

  const int m = blockIdx.z;
  const int p = m >> 5, b = m & 31;
  const int setA = (p == 1 || p == 3) ? 0 : 1;
  const int setB = (p <= 1) ? 2 : setA;
  const unsigned short* YA = Y + ((size_t)(setA * BATCH + b)) * SEQ * 256;
  const unsigned short* YB = Y + ((size_t)(setB * BATCH + b)) * SEQ * 256;
  const int i0 = blockIdx.x * 128, j0 = blockIdx.y * 128;

  const int t = threadIdx.x;
  const int w = t >> 6, l = t & 63;
  const int wr = w >> 1, wc = w & 1;

  f32x4 acc[4][4];
#pragma unroll
  for (int a = 0; a < 4; ++a)
#pragma unroll
    for (int c = 0; c < 4; ++c) acc[a][c] = (f32x4){0.f, 0.f, 0.f, 0.f};

  // staging lane geometry (same for every slab): wave-issue wi covers rows
  // wi*8..wi*8+7; lane l -> row wi*8+(l>>3), 16B chunk (l&7), source col
  // pre-swizzled by ((row&7)<<4) so swizzled ds_reads see linear data.
  const int srow_off = l >> 3;                    // 0..7
  const int scb      = ((l & 7) * 16) ^ ((srow_off & 7) * 16);  // bytes 0..127

  for (int slab = 0; slab < 4; ++slab) {
    if (slab) __syncthreads();                    // prev compute done
#pragma unroll
    for (int q = 0; q < 4; ++q) {
      int wi = w * 4 + q;
      int r = wi * 8 + srow_off;
      const unsigned short* gA = YA + (size_t)(i0 + r) * 256 + slab * 64 + (scb >> 1);
      const unsigned short* gB = YB + (size_t)(j0 + r) * 256 + slab * 64 + (scb >> 1);
      __builtin_amdgcn_global_load_lds((gas_void*)gA, (las_void*)(As + wi * 512), 16, 0, 0);
      __builtin_amdgcn_global_load_lds((gas_void*)gB, (las_void*)(Bs + wi * 512), 16, 0, 0);
    }
    asm volatile("s_waitcnt vmcnt(0)" ::: "memory");
    __syncthreads();

#pragma unroll
    for (int ks = 0; ks < 2; ++ks) {
      bf16x8 af[4], bfr[4];
#pragma unroll
      for (int f = 0; f < 4; ++f) {
        int ra = wr * 64 + f * 16 + (l & 15);
        int ca = (ks * 64 + (l >> 4) * 16) ^ ((ra & 7) << 4);
        af[f] = *(const bf16x8*)((const char*)As + ra * 128 + ca);
        int rb = wc * 64 + f * 16 + (l & 15);
        int cb = (ks * 64 + (l >> 4) * 16) ^ ((rb & 7) << 4);
        bfr[f] = *(const bf16x8*)((const char*)Bs + rb * 128 + cb);
      }
#pragma unroll
      for (int fm = 0; fm < 4; ++fm)
#pragma unroll
        for (int fn = 0; fn < 4; ++fn)
          acc[fm][fn] = __builtin_amdgcn_mfma_f32_16x16x32_bf16(
              af[fm], bfr[fn], acc[fm][fn], 0, 0, 0);
    }
  }

  float* Dm = Dsk + (size_t)m * MAT_ELEMS;
#pragma unroll
  for (int fm = 0; fm < 4; ++fm) {
#pragma unroll
    for (int fn = 0; fn < 4; ++fn) {
#pragma unroll
      for (int q = 0; q < 4; ++q) {
        int ia = i0 + wr * 64 + fm * 16 + (l >> 4) * 4 + q;
        int ja = j0 + wc * 64 + fn * 16 + (l & 15);
        float dp = (1.0f - acc[fm][fn][q]) * LOG2E;
        Dm[(((ia + ja + 2) & 511) << 9) + ia] = dp;
      }
    }
  }
}

// ---------------------------------------------------------------------------
// Kernel 3: staggered-wave soft-DTW (8 waves, wave w lags w*32 steps).
// Boundary values buffered in registers, flushed as 8x ds_write_b128 per
// phase (keeps the per-step lgkm chain = shfl only).
// Ring: [wave][chunk=producerPhase&3][slot=(s-1)&31].
// ---------------------------------------------------------------------------
#define JP 32
#define NPH 40

__device__ __forceinline__ void wg_barrier() {
  asm volatile("s_waitcnt lgkmcnt(0)" ::: "memory");
  __builtin_amdgcn_s_barrier();
  asm volatile("" ::: "memory");
}

__global__ __launch_bounds__(512) void dtw_kernel(
    const float* __restrict__ Dsk, float* __restrict__ raw) {
  __shared__ float ring[8][4][32];
  const int tid  = threadIdx.x;
  const int w    = tid >> 6;
  const int lane = tid & 63;
  const int m    = blockIdx.x;
  const float* Dm = Dsk + (size_t)m * MAT_ELEMS;

  ((float*)ring)[tid]       = BIGP;
  ((float*)ring)[tid + 512] = BIGP;
  __syncthreads();

  const int i = tid + 1;
  const bool is0  = (lane == 0);
  const bool is63 = (lane == 63);
  const int  jj   = (lane <= JP) ? lane : JP;

  float v = BIGP, shp = BIGP, shp2 = BIGP;
  float res = 0.0f;
  float nvh[JP];

  float dA[JP], dB[JP];
  {
    int base0 = (0 - w) * JP;
#pragma unroll
    for (int q = 0; q < JP; ++q) {
      int L = base0 + 1 + q;
      dA[q] = Dm[((L & 511) << 9) + tid];
    }
  }

#define PHASE(P_, DC_, DN_)                                                   \
  {                                                                           \
    const int base = ((P_) - w) * JP;                                         \
    float bvec;                                                               \
    if (w == 0) {                                                             \
      int s = base - 1 + jj;                                                  \
      bvec = (s == 0) ? 0.0f : BIGP;                                          \
    } else {                                                                  \
      int s = base - 1 + jj;                                                  \
      int cidx = (((s - 1) >> 5) + w - 1) & 3;                                \
      int slot = (s - 1) & 31;                                                \
      bvec = ring[w - 1][cidx][slot];                                         \
    }                                                                         \
    _Pragma("unroll")                                                         \
    for (int q = 0; q < JP; ++q) {                                            \
      int L = base + JP + 1 + q;                                              \
      DN_[q] = Dm[((L & 511) << 9) + tid];                                    \
    }                                                                         \
    _Pragma("unroll")                                                         \
    for (int q = 1; q <= JP; ++q) {                                           \
      float s_a = __int_as_float(                                             \
          __builtin_amdgcn_readlane(__float_as_int(bvec), q));                \
      float s_c = __int_as_float(                                             \
          __builtin_amdgcn_readlane(__float_as_int(bvec), q - 1));            \
      float a = is0 ? s_a : shp;                                              \
      float c = is0 ? s_c : shp2;                                             \
      float b = v;                                                            \
      float mn = fminf(fminf(a, b), c);                                       \
      float sum = EXP2F(mn - a) + EXP2F(mn - b) + EXP2F(mn - c);              \
      float nv = DC_[q - 1] + (mn - LOG2F(sum));                              \
      int L = base + q;                                                       \
      unsigned ju = (unsigned)(L - i - 1);                                    \
      nv = (ju < 512u) ? nv : BIGP;                                           \
      nvh[q - 1] = nv;                                                        \
      if (L == 1024 && tid == 511) res = nv;                                  \
      shp2 = shp;                                                             \
      shp = __shfl_up(nv, 1);                                                 \
      v = nv;                                                                 \
    }                                                                         \
    if (is63) {                                                               \
      float4* dst = (float4*)&ring[w][(P_) & 3][0];                           \
      _Pragma("unroll")                                                       \
      for (int r4 = 0; r4 < 8; ++r4)                                          \
        dst[r4] = make_float4(nvh[4 * r4], nvh[4 * r4 + 1],                   \
                              nvh[4 * r4 + 2], nvh[4 * r4 + 3]);              \
    }                                                                         \
    wg_barrier();                                                             \
  }

  for (int p = 0; p < NPH; p += 2) {
    PHASE(p, dA, dB)
    PHASE(p + 1, dB, dA)
  }
#undef PHASE

  if (tid == 511) raw[m] = res * LN2;
}

// ---------------------------------------------------------------------------
// Kernel 4: combine + MSE
// ---------------------------------------------------------------------------
__global__ __launch_bounds__(64) void combine_kernel(
    const float* __restrict__ raw, const float* __restrict__ labels,
    float* __restrict__ out) {
  int lane = threadIdx.x;
  float val = 0.0f;
  if (lane < BATCH) {
    float r0 = raw[0 * BATCH + lane];
    float r1 = raw[1 * BATCH + lane];
    float r2 = raw[2 * BATCH + lane];
    float r3 = raw[3 * BATCH + lane];
    float diff = r0 - r1 - 0.5f * r2 + 0.5f * r3;
    float e = diff - labels[lane];
    val = e * e;
  }
#pragma unroll
  for (int off = 32; off; off >>= 1) val += __shfl_xor(val, off);
  if (lane == 0) out[0] = val * (1.0f / BATCH);
}

// ---------------------------------------------------------------------------
extern "C" void kernel_launch(void* const* d_in, const int* in_sizes, int n_in,
                              void* d_out, int out_size, void* d_ws, size_t ws_size,
                              hipStream_t stream) {
  const float* TGT = (const float*)d_in[0];
  const float* OTH = (const float*)d_in[1];
  const float* X   = (const float*)d_in[2];
  const float* labels = (const float*)d_in[3];
  float* out = (float*)d_out;

  char* ws = (char*)d_ws;
  float* Dsk = (float*)ws;                                        // 128 MB
  unsigned short* Y = (unsigned short*)(ws + (size_t)NMAT * MAT_ELEMS * 4); // 25.2 MB
  float* raw = (float*)(ws + (size_t)NMAT * MAT_ELEMS * 4 +
                        (size_t)3 * BATCH * SEQ * 256 * 2);

  hipLaunchKernelGGL(prep_kernel, dim3((3 * BATCH * SEQ) / 4), dim3(256), 0, stream,
                     TGT, OTH, X, Y);
  hipLaunchKernelGGL(costmm_kernel, dim3(4, 4, NMAT), dim3(256), 0, stream, Y, Dsk);
  hipLaunchKernelGGL(dtw_kernel, dim3(NMAT), dim3(512), 0, stream, Dsk, raw);
  hipLaunchKernelGGL(combine_kernel, dim3(1), dim3(64), 0, stream, raw, labels, out);
}